// Round 1
// baseline (724.393 us; speedup 1.0000x reference)
//
#include <hip/hip_runtime.h>
#include <math.h>

// CRF forward partition scan.
// B=512 batches, S=1024 steps, T=48 tags.
// One 64-lane wave per batch element. Lane j owns tag j (lanes 48..63 clamped).
// Per-lane registers hold T[:,j] and exp(T[:,j]) (constant across steps).
// Cross-lane exchange of part_i / exp(a_i) via LDS broadcast reads.

constexpr int kB = 512;
constexpr int kS = 1024;
constexpr int kT = 48;

__global__ __launch_bounds__(64) void crf_fwd(
    const float* __restrict__ feats,   // [B, S, T] fp32
    const int*   __restrict__ mask,    // [B, S] int32 (bool)
    const float* __restrict__ trans,   // [T, T] fp32
    float*       __restrict__ out)     // [1 + B]; we write out[1+b]
{
    const int b    = blockIdx.x;
    const int lane = threadIdx.x;
    const int j    = (lane < kT) ? lane : (kT - 1);  // clamp idle lanes

    __shared__ alignas(16) float p_sh[64];   // part_i
    __shared__ alignas(16) float ea_sh[64];  // exp(part_i - e_i - M_i)

    // Column j of transition and its exp, resident in VGPRs for all steps.
    float Tc[kT];
    float Ec[kT];
#pragma unroll
    for (int i = 0; i < kT; ++i) {
        Tc[i] = trans[i * kT + j];
        Ec[i] = __expf(Tc[i]);
    }

    const float* fb = feats + (size_t)b * kS * kT;
    const int*   mb = mask  + (size_t)b * kS;

    // part0 = emit[0] + transition[T-2, :]
    float part = fb[j] + Tc[kT - 2];
    p_sh[lane] = part;
    __syncthreads();

    // software prefetch of next step's emission + mask (hides VMEM latency)
    float e_next = fb[kT + j];
    int   m_next = mb[1];

    for (int t = 1; t < kS; ++t) {
        const float e  = e_next;
        const int   mk = m_next;
        const int   tn = (t + 1 < kS) ? (t + 1) : t;
        e_next = fb[tn * kT + j];
        m_next = mb[tn];

        if (mk) {  // wave-uniform branch: skip masked-out steps entirely
            // pass 1: M_j = max_i (T[i,j] + part_i)  -- LDS broadcast reads
            const float4* p4 = (const float4*)p_sh;
            float M0 = -INFINITY, M1 = -INFINITY, M2 = -INFINITY, M3 = -INFINITY;
#pragma unroll
            for (int i = 0; i < kT; i += 4) {
                const float4 p = p4[i >> 2];
                M0 = fmaxf(M0, Tc[i + 0] + p.x);
                M1 = fmaxf(M1, Tc[i + 1] + p.y);
                M2 = fmaxf(M2, Tc[i + 2] + p.z);
                M3 = fmaxf(M3, Tc[i + 3] + p.w);
            }
            const float M = fmaxf(fmaxf(M0, M1), fmaxf(M2, M3));

            // lane i publishes exp(part_i - e_i - M_i)
            const float ea = __expf(part - e - M);
            ea_sh[lane] = ea;
            __syncthreads();  // B1: ea visible; all pass-1 reads of p_sh done

            // pass 2: S_j = sum_i exp(T[i,j]) * ea_i   (pure FMA dot product)
            const float4* q4 = (const float4*)ea_sh;
            float S0 = 0.f, S1 = 0.f, S2 = 0.f, S3 = 0.f;
#pragma unroll
            for (int i = 0; i < kT; i += 4) {
                const float4 q = q4[i >> 2];
                S0 = fmaf(Ec[i + 0], q.x, S0);
                S1 = fmaf(Ec[i + 1], q.y, S1);
                S2 = fmaf(Ec[i + 2], q.z, S2);
                S3 = fmaf(Ec[i + 3], q.w, S3);
            }
            const float Ssum = (S0 + S1) + (S2 + S3);

            // val_j = 2*e_j + M_j + log(S_j); mask true here so part <- val
            part = 2.0f * e + M + __logf(Ssum);
            p_sh[lane] = part;
            __syncthreads();  // B2: part visible for next step's pass 1
        }
    }

    // Final transition-only step; only end_value[:, T-1] is needed, but all
    // M_i are required, so run both passes.
    {
        const float4* p4 = (const float4*)p_sh;
        float M0 = -INFINITY, M1 = -INFINITY, M2 = -INFINITY, M3 = -INFINITY;
#pragma unroll
        for (int i = 0; i < kT; i += 4) {
            const float4 p = p4[i >> 2];
            M0 = fmaxf(M0, Tc[i + 0] + p.x);
            M1 = fmaxf(M1, Tc[i + 1] + p.y);
            M2 = fmaxf(M2, Tc[i + 2] + p.z);
            M3 = fmaxf(M3, Tc[i + 3] + p.w);
        }
        const float M = fmaxf(fmaxf(M0, M1), fmaxf(M2, M3));
        const float ea = __expf(part - M);   // no emission term in final step
        ea_sh[lane] = ea;
        __syncthreads();

        const float4* q4 = (const float4*)ea_sh;
        float S0 = 0.f, S1 = 0.f, S2 = 0.f, S3 = 0.f;
#pragma unroll
        for (int i = 0; i < kT; i += 4) {
            const float4 q = q4[i >> 2];
            S0 = fmaf(Ec[i + 0], q.x, S0);
            S1 = fmaf(Ec[i + 1], q.y, S1);
            S2 = fmaf(Ec[i + 2], q.z, S2);
            S3 = fmaf(Ec[i + 3], q.w, S3);
        }
        const float Ssum = (S0 + S1) + (S2 + S3);
        const float val = M + __logf(Ssum);
        if (lane == kT - 1) out[1 + b] = val;  // score[b] = end_value[b, -1]
    }
}

// out[0] = sum(score). Single wave; no barriers needed.
__global__ __launch_bounds__(64) void sum_scores(
    const float* __restrict__ sc, float* __restrict__ out)
{
    float s = 0.f;
    for (int i = (int)threadIdx.x; i < kB; i += 64) s += sc[i];
#pragma unroll
    for (int off = 32; off > 0; off >>= 1) s += __shfl_down(s, off);
    if (threadIdx.x == 0) out[0] = s;
}

extern "C" void kernel_launch(void* const* d_in, const int* in_sizes, int n_in,
                              void* d_out, int out_size, void* d_ws, size_t ws_size,
                              hipStream_t stream) {
    const float* feats = (const float*)d_in[0];
    const int*   mask  = (const int*)d_in[1];
    const float* trans = (const float*)d_in[2];
    float*       out   = (float*)d_out;

    crf_fwd<<<dim3(kB), dim3(64), 0, stream>>>(feats, mask, trans, out);
    sum_scores<<<dim3(1), dim3(64), 0, stream>>>(out + 1, out);
}